// Round 11
// baseline (206.797 us; speedup 1.0000x reference)
//
#include <hip/hip_runtime.h>
#include <math.h>

#define EPSF 1e-8f
#define BIGF 1e30f
#define SEGSZ 216      // cleanup/fallback scan segment
#define NSEGC 64       // cull segments per tile
#define NSEGR 8        // raster segments per tile (each covers NSEGC/NSEGR cull slices)
#define SLICES (NSEGC / NSEGR)
#define MAXTILES 1024

__device__ __forceinline__ float fastrcp(float x) {
    float y;
    asm("v_rcp_f32 %0, %1" : "=v"(y) : "v"(x));   // ~1 ulp; perf-filter only
    return y;
}

// ---------------------------------------------------------------------------
// Kernel 1: project vertices. Bit-exact replica of the numpy f32 op sequence.
// ---------------------------------------------------------------------------
__global__ void k_prep_verts(const float* __restrict__ verts,
                             const float* __restrict__ Km,
                             const float* __restrict__ Rm,
                             const float* __restrict__ tv,
                             float* __restrict__ sx, float* __restrict__ sy,
                             float* __restrict__ sz, int nV)
{
    int v = blockIdx.x * blockDim.x + threadIdx.x;
    if (v >= nV) return;
    float vx = verts[3*v+0], vy = verts[3*v+1], vz = verts[3*v+2];
    float a;
    a = __fadd_rn(__fmul_rn(vx, Rm[0]), __fmul_rn(vy, Rm[1]));
    a = __fadd_rn(a, __fmul_rn(vz, Rm[2]));
    float c0 = __fadd_rn(a, tv[0]);
    a = __fadd_rn(__fmul_rn(vx, Rm[3]), __fmul_rn(vy, Rm[4]));
    a = __fadd_rn(a, __fmul_rn(vz, Rm[5]));
    float c1 = __fadd_rn(a, tv[1]);
    a = __fadd_rn(__fmul_rn(vx, Rm[6]), __fmul_rn(vy, Rm[7]));
    a = __fadd_rn(a, __fmul_rn(vz, Rm[8]));
    float c2 = __fadd_rn(a, tv[2]);

    float u0 = __fadd_rn(__fadd_rn(__fmul_rn(c0, Km[0]), __fmul_rn(c1, Km[1])),
                         __fmul_rn(c2, Km[2]));
    float u1 = __fadd_rn(__fadd_rn(__fmul_rn(c0, Km[3]), __fmul_rn(c1, Km[4])),
                         __fmul_rn(c2, Km[5]));
    sx[v] = __fdiv_rn(u0, c2);
    sy[v] = __fdiv_rn(u1, c2);
    sz[v] = c2;
}

// ---------------------------------------------------------------------------
// Kernel 2: per-face setup + zwin init + ovf init (grid-stride).
// rec[3f+0] = {y12, x21, y20, x02}
// rec[3f+1] = {x2,  y2,  denom, z0}
// rec[3f+2] = {z1,  z2,  face_id_bits, zmin}
// ---------------------------------------------------------------------------
__global__ __launch_bounds__(64) void k_prep_faces(
    const int* __restrict__ faces,
    const float* __restrict__ sx, const float* __restrict__ sy,
    const float* __restrict__ sz,
    float4* __restrict__ rec, float4* __restrict__ box,
    unsigned long long* __restrict__ zwin, unsigned* __restrict__ ovf,
    int nF, int P, int nTiles)
{
    int f = blockIdx.x * blockDim.x + threadIdx.x;
    int stride = gridDim.x * blockDim.x;
    unsigned long long initpk =
        ((unsigned long long)__float_as_uint(BIGF) << 32) | 0x7fffffffu;
    for (int i = f; i < P; i += stride) zwin[i] = initpk;
    for (int i = f; i < nTiles; i += stride) ovf[i] = 0u;
    if (f >= nF) return;

    int ia = faces[3*f+0], ib = faces[3*f+1], ic = faces[3*f+2];
    float x0 = sx[ia], y0 = sy[ia], z0 = sz[ia];
    float x1 = sx[ib], y1 = sy[ib], z1 = sz[ib];
    float x2 = sx[ic], y2 = sy[ic], z2 = sz[ic];
    float y12 = __fsub_rn(y1, y2);
    float x21 = __fsub_rn(x2, x1);
    float y20 = __fsub_rn(y2, y0);
    float x02 = __fsub_rn(x0, x2);
    float y02 = __fsub_rn(y0, y2);
    float dn  = __fadd_rn(__fmul_rn(y12, x02), __fmul_rn(x21, y02));
    float zmin = fminf(fminf(z0, z1), z2);
    bool valid = (fabsf(dn) > EPSF) && (zmin > EPSF);
    float bxmin, bxmax, bymin, bymax;
    if (valid) {
        bxmin = fminf(fminf(x0, x1), x2) - 0.5f;
        bxmax = fmaxf(fmaxf(x0, x1), x2) + 0.5f;
        bymin = fminf(fminf(y0, y1), y2) - 0.5f;
        bymax = fmaxf(fmaxf(y0, y1), y2) + 0.5f;
    } else {
        bxmin = BIGF; bxmax = -BIGF; bymin = BIGF; bymax = -BIGF;
    }
    rec[3*f+0] = make_float4(y12, x21, y20, x02);
    rec[3*f+1] = make_float4(x2, y2, dn, z0);
    rec[3*f+2] = make_float4(z1, z2, __int_as_float(f), zmin);
    box[f]     = make_float4(bxmin, bxmax, bymin, bymax);
}

// ---------------------------------------------------------------------------
// Kernel 3: tile-centric segmented cull. Grid (tiles/4, NSEGC); wave =
// (tile, face-window). bbox + conservative edge-vs-tile test; ballot-compacts
// ids into PRIVATE slice list[t*CAP + seg*SUBCAP..]. No atomics, no LDS.
// ---------------------------------------------------------------------------
__global__ __launch_bounds__(256) void k_cull(
    const float4* __restrict__ box, const float4* __restrict__ rec,
    unsigned* __restrict__ cntseg, unsigned* __restrict__ ovf,
    unsigned short* __restrict__ list,
    int nF, int tilesX, int nTiles, int CAP, int SUBCAP)
{
    int wid  = threadIdx.x >> 6;
    int lane = threadIdx.x & 63;
    int tile = blockIdx.x * 4 + wid;
    if (tile >= nTiles) return;
    int seg  = blockIdx.y;
    int segw = (nF + NSEGC - 1) / NSEGC;
    int fbeg = seg * segw;
    int fend = min(nF, fbeg + segw);

    int tileX = tile % tilesX, tileY = tile / tilesX;
    float rx0 = (float)(tileX * 8) + 0.5f;
    float rx1 = rx0 + 7.0f;
    float ry0 = (float)(tileY * 8) + 0.5f;
    float ry1 = ry0 + 7.0f;
    float cx  = (float)(tileX * 8) + 4.0f;   // pixel centers span cx +/- 3.5
    float cy  = (float)(tileY * 8) + 4.0f;

    unsigned short* ml = list + (size_t)tile * CAP + (size_t)seg * SUBCAP;
    int c = 0;

    for (int base = fbeg; base < fend; base += 64) {
        int f = base + lane;
        bool pass = false;
        if (f < fend) {
            float4 cb = box[f];
            pass = (cb.x <= rx1) && (cb.y >= rx0) && (cb.z <= ry1) && (cb.w >= ry0);
        }
        if (pass) {
            float4 r0 = rec[3*f+0];
            float4 r1 = rec[3*f+1];
            // conservative edge-vs-tile reject (3.6 > 3.5 px; perf-only)
            float s  = (r1.z > 0.0f) ? 1.0f : -1.0f;
            float dx = cx - r1.x, dy = cy - r1.y;
            float n0c = r0.x * dx + r0.y * dy;
            float n1c = r0.z * dx + r0.w * dy;
            float t0 = s * n0c + 3.6f * (fabsf(r0.x) + fabsf(r0.y));
            float t1 = s * n1c + 3.6f * (fabsf(r0.z) + fabsf(r0.w));
            float t2 = s * (r1.z - n0c - n1c)
                     + 3.6f * (fabsf(r0.x + r0.z) + fabsf(r0.y + r0.w));
            pass = (t0 >= 0.0f) && (t1 >= 0.0f) && (t2 >= 0.0f);
        }
        unsigned long long m = __ballot(pass);
        if (pass) {
            unsigned slot = (unsigned)(c + __popcll(m & ((1ull << lane) - 1ull)));
            if (slot < (unsigned)SUBCAP) ml[slot] = (unsigned short)f;
        }
        c += (int)__popcll(m);
    }
    if (lane == 0) {
        cntseg[tile * NSEGC + seg] = (unsigned)c;
        if (c > SUBCAP) ovf[tile] = 1u;   // benign race: all writers store 1
    }
}

// ---------------------------------------------------------------------------
// Kernel 4: binned raster. Grid (tiles/4, NSEGR); each wave sequentially
// processes SLICES cull slices (~8x more work/wave than 1:1), so its running
// bd warms locally and per-wave overhead (seed read, atomic) is amortized.
// 4-wide zmin group-skip: one b128 broadcast + one ballot per 4 faces.
// Exact path byte-identical to reference; winner = commutative (depth,id) min.
// ---------------------------------------------------------------------------
__global__ __launch_bounds__(256) void k_raster_bin(
    const float4* __restrict__ rec,
    const unsigned* __restrict__ cntseg, const unsigned short* __restrict__ list,
    unsigned long long* __restrict__ zwin,
    int nF, int W, int H, int tilesX, int nTiles, int CAP, int SUBCAP)
{
    __shared__ float  sM[4][64];        // zmin (1 KB), read as float4 groups
    __shared__ float4 sZ[4][64];        // r2   (4 KB)
    __shared__ float4 sE[4][64][2];     // r0,r1 (8 KB)
    int wid  = threadIdx.x >> 6;
    int lane = threadIdx.x & 63;
    int tile = blockIdx.x * 4 + wid;
    if (tile >= nTiles) return;
    int rseg = blockIdx.y;

    int tileX = tile % tilesX, tileY = tile / tilesX;
    int tx = lane & 7, ty = lane >> 3;
    int pxi = tileX * 8 + tx;
    int pyi = tileY * 8 + ty;
    float px = (float)pxi + 0.5f;
    float py = (float)pyi + 0.5f;

    int pidx = pyi * W + pxi;
    unsigned long long seed = zwin[pidx];   // stale reads sound (monotone min)
    float bd = __uint_as_float((unsigned)(seed >> 32));
    int   bf = (int)(unsigned)(seed & 0xffffffffu);

    const float4* sM4g = (const float4*)sM[wid];

    for (int s = 0; s < SLICES; ++s) {
        int cs = rseg * SLICES + s;
        int sc = min((int)cntseg[tile * NSEGC + cs], SUBCAP);
        if (sc <= 0) continue;
        const unsigned short* ml =
            list + (size_t)tile * CAP + (size_t)cs * SUBCAP;

        for (int cb = 0; cb < sc; cb += 64) {
            int idx = cb + lane;
            if (idx < sc) {
                int f = (int)ml[idx];
                float4 c0 = rec[3*f+0], c1 = rec[3*f+1], c2 = rec[3*f+2];
                int slot = idx - cb;
                sM[wid][slot]    = c2.w;
                sZ[wid][slot]    = c2;
                sE[wid][slot][0] = c0;
                sE[wid][slot][1] = c1;
            }
            int scnt2 = min(64, sc - cb);

            for (int g = 0; g < scnt2; g += 4) {
                // group skip: min of 4 zmins (stale tail slots only weaken
                // the skip -> conservative), one broadcast + one ballot.
                float4 z4 = sM4g[g >> 2];
                float zg = fminf(fminf(z4.x, z4.y), fminf(z4.z, z4.w));
                if (!__any(zg <= __fmul_rn(bd, 1.001f))) continue;
                int jend = min(scnt2, g + 4);
                for (int j = g; j < jend; ++j) {
                    if (!__any(sM[wid][j] <= __fmul_rn(bd, 1.001f))) continue;
                    float4 r2 = sZ[wid][j];
                    float4 r0 = sE[wid][j][0];
                    float4 r1 = sE[wid][j][1];

                    float dx = __fsub_rn(px, r1.x);
                    float dy = __fsub_rn(py, r1.y);
                    float n0 = __fadd_rn(__fmul_rn(r0.x, dx), __fmul_rn(r0.y, dy));
                    float n1 = __fadd_rn(__fmul_rn(r0.z, dx), __fmul_rn(r0.w, dy));
                    float dn = r1.z;
                    bool dpos = dn > 0.0f;
                    bool in0 = (n0 == 0.0f) || ((n0 > 0.0f) == dpos);  // n0/dn >= 0
                    bool in1 = (n1 == 0.0f) || ((n1 > 0.0f) == dpos);
                    bool cand = in0 && in1;
                    if (cand) {
                        float rdn = fastrcp(dn);
                        float w0a = n0 * rdn, w1a = n1 * rdn;
                        float w2a = 1.0f - w0a - w1a;
                        float ss  = 1.0f + fabsf(w0a) + fabsf(w1a);
                        cand = (w2a >= -1e-4f * ss);       // err(w2a) <= 3e-7*ss
                        if (cand) {
                            float iza = w0a * fastrcp(r1.w) + w1a * fastrcp(r2.x)
                                      + w2a * fastrcp(r2.y);
                            float da  = fastrcp(iza);
                            cand = (da <= __fmul_rn(bd, 1.001f)); // err ~1.5e-4
                        }
                    }
                    if (cand) {   // exact path: byte-identical reference ops
                        float w0 = __fdiv_rn(n0, dn);
                        float w1 = __fdiv_rn(n1, dn);
                        float w2 = __fsub_rn(__fsub_rn(1.0f, w0), w1);
                        if (w2 >= 0.0f) {
                            float a  = __fdiv_rn(w0, r1.w);
                            float b2 = __fdiv_rn(w1, r2.x);
                            float c  = __fdiv_rn(w2, r2.y);
                            float iz = __fadd_rn(__fadd_rn(a, b2), c);
                            if (iz > EPSF) {
                                float d = __fdiv_rn(1.0f, iz);
                                int  fc = __float_as_int(r2.z);
                                if ((d < bd) || ((d == bd) && (fc < bf))) {
                                    bd = d; bf = fc;
                                }
                            }
                        }
                    }
                }
            }
        }
    }

    unsigned long long pk =
        ((unsigned long long)__float_as_uint(bd) << 32) | (unsigned int)bf;
    if (pk < seed) atomicMin(&zwin[pidx], pk);
}

// ---------------------------------------------------------------------------
// Kernel 4b: full-scan raster. (a) fallback (gate==nullptr), (b) overflow
// cleanup (gate!=nullptr: only tiles with ovf flag rescan ALL faces exactly).
// ---------------------------------------------------------------------------
__global__ __launch_bounds__(256) void k_raster_scan(
    const float4* __restrict__ rec, const float4* __restrict__ box,
    unsigned long long* __restrict__ zwin, int nF, int W, int H,
    int tilesX, int nTiles, const unsigned* __restrict__ gate)
{
    __shared__ float4 slds[4][64 * 3];
    int wid  = threadIdx.x >> 6;
    int lane = threadIdx.x & 63;
    int tile = blockIdx.x * 4 + wid;
    if (tile >= nTiles) return;
    if (gate && gate[tile] == 0u) return;   // cleanup gate
    int tileX = tile % tilesX, tileY = tile / tilesX;
    int tx = lane & 7, ty = lane >> 3;
    int pxi = tileX * 8 + tx;
    int pyi = tileY * 8 + ty;
    float px = (float)pxi + 0.5f;
    float py = (float)pyi + 0.5f;
    float rx0 = (float)(tileX * 8) + 0.5f;
    float rx1 = rx0 + 7.0f;
    float ry0 = (float)(tileY * 8) + 0.5f;
    float ry1 = ry0 + 7.0f;
    float cx  = (float)(tileX * 8) + 4.0f;
    float cy  = (float)(tileY * 8) + 4.0f;

    int beg = blockIdx.y * SEGSZ;
    int end = min(nF, beg + SEGSZ);
    if (beg >= end) return;

    int pidx = pyi * W + pxi;
    unsigned long long seed = zwin[pidx];
    float bd = __uint_as_float((unsigned)(seed >> 32));
    int   bf = (int)(unsigned)(seed & 0xffffffffu);

    float4* my = slds[wid];
    float4 pb, p0, p1, p2;
    {
        int f = beg + lane;
        int fc = (f < end) ? f : (end - 1);
        pb = box[fc];
        p0 = rec[3*fc+0]; p1 = rec[3*fc+1]; p2 = rec[3*fc+2];
    }
    for (int base = beg; base < end; base += 64) {
        float4 cb = pb, c0 = p0, c1 = p1, c2 = p2;
        if (base + 64 < end) {
            int f = base + 64 + lane;
            int fc = (f < end) ? f : (end - 1);
            pb = box[fc];
            p0 = rec[3*fc+0]; p1 = rec[3*fc+1]; p2 = rec[3*fc+2];
        }
        int f = base + lane;
        bool pass = (f < end) &&
                    (cb.x <= rx1) && (cb.y >= rx0) && (cb.z <= ry1) && (cb.w >= ry0);
        if (pass) {
            float s  = (c1.z > 0.0f) ? 1.0f : -1.0f;
            float dx = cx - c1.x, dy = cy - c1.y;
            float n0c = c0.x * dx + c0.y * dy;
            float n1c = c0.z * dx + c0.w * dy;
            float t0 = s * n0c + 3.6f * (fabsf(c0.x) + fabsf(c0.y));
            float t1 = s * n1c + 3.6f * (fabsf(c0.z) + fabsf(c0.w));
            float t2 = s * (c1.z - n0c - n1c)
                     + 3.6f * (fabsf(c0.x + c0.z) + fabsf(c0.y + c0.w));
            pass = (t0 >= 0.0f) && (t1 >= 0.0f) && (t2 >= 0.0f);
        }
        unsigned long long m = __ballot(pass);
        if (pass) {
            int slot = __popcll(m & ((1ull << lane) - 1ull));
            my[slot*3+0] = c0; my[slot*3+1] = c1; my[slot*3+2] = c2;
        }
        int cnt = (int)__popcll(m);
        for (int j = 0; j < cnt; ++j) {
            float4 r0 = my[j*3+0], r1 = my[j*3+1], r2 = my[j*3+2];
            if (!__any(r2.w <= __fmul_rn(bd, 1.001f))) continue;
            float dx = __fsub_rn(px, r1.x);
            float dy = __fsub_rn(py, r1.y);
            float n0 = __fadd_rn(__fmul_rn(r0.x, dx), __fmul_rn(r0.y, dy));
            float n1 = __fadd_rn(__fmul_rn(r0.z, dx), __fmul_rn(r0.w, dy));
            float dn = r1.z;
            bool dpos = dn > 0.0f;
            bool in0 = (n0 == 0.0f) || ((n0 > 0.0f) == dpos);
            bool in1 = (n1 == 0.0f) || ((n1 > 0.0f) == dpos);
            bool cand = in0 && in1;
            if (cand) {
                float rdn = fastrcp(dn);
                float w0a = n0 * rdn, w1a = n1 * rdn;
                float w2a = 1.0f - w0a - w1a;
                float ss  = 1.0f + fabsf(w0a) + fabsf(w1a);
                cand = (w2a >= -1e-4f * ss);
                if (cand) {
                    float iza = w0a * fastrcp(r1.w) + w1a * fastrcp(r2.x)
                              + w2a * fastrcp(r2.y);
                    float da  = fastrcp(iza);
                    cand = (da <= __fmul_rn(bd, 1.001f));
                }
            }
            if (cand) {
                float w0 = __fdiv_rn(n0, dn);
                float w1 = __fdiv_rn(n1, dn);
                float w2 = __fsub_rn(__fsub_rn(1.0f, w0), w1);
                if (w2 >= 0.0f) {
                    float a  = __fdiv_rn(w0, r1.w);
                    float b2 = __fdiv_rn(w1, r2.x);
                    float c  = __fdiv_rn(w2, r2.y);
                    float iz = __fadd_rn(__fadd_rn(a, b2), c);
                    if (iz > EPSF) {
                        float d = __fdiv_rn(1.0f, iz);
                        int  fc = __float_as_int(r2.z);
                        if ((d < bd) || ((d == bd) && (fc < bf))) { bd = d; bf = fc; }
                    }
                }
            }
        }
    }
    unsigned long long pk =
        ((unsigned long long)__float_as_uint(bd) << 32) | (unsigned int)bf;
    if (pk < seed) atomicMin(&zwin[pidx], pk);
}

// ---------------------------------------------------------------------------
// Kernel 5: shade. One thread per pixel; recompute winner bary (bit-identical
// op sequence) and trilinear-sample its 8^3 texture.
// ---------------------------------------------------------------------------
__global__ __launch_bounds__(128) void k_shade(
    const float4* __restrict__ rec,
    const unsigned long long* __restrict__ zwin,
    const float* __restrict__ tex, const float* __restrict__ bgc,
    float* __restrict__ out, int W, int H)
{
    int p = blockIdx.x * blockDim.x + threadIdx.x;
    int P = W * H;
    if (p >= P) return;
    int pxi = p % W, pyi = p / W;
    float px = (float)pxi + 0.5f;
    float py = (float)pyi + 0.5f;

    unsigned long long pk = zwin[p];
    float o0, o1, o2, oa;
    if ((unsigned)(pk >> 32) != __float_as_uint(BIGF)) {
        int f = (int)(pk & 0xffffffffu);
        float4 r0 = rec[3*f+0];
        float4 r1 = rec[3*f+1];
        float4 r2 = rec[3*f+2];
        float dx = __fsub_rn(px, r1.x);
        float dy = __fsub_rn(py, r1.y);
        float n0 = __fadd_rn(__fmul_rn(r0.x, dx), __fmul_rn(r0.y, dy));
        float n1 = __fadd_rn(__fmul_rn(r0.z, dx), __fmul_rn(r0.w, dy));
        float w0 = __fdiv_rn(n0, r1.z);
        float w1 = __fdiv_rn(n1, r1.z);
        float w2 = __fsub_rn(__fsub_rn(1.0f, w0), w1);
        float c0 = __fdiv_rn(w0, fmaxf(r1.w, EPSF));
        float c1 = __fdiv_rn(w1, fmaxf(r2.x, EPSF));
        float c2 = __fdiv_rn(w2, fmaxf(r2.y, EPSF));
        float s  = __fadd_rn(__fadd_rn(c0, c1), c2);
        s = fmaxf(s, EPSF);
        c0 = __fdiv_rn(c0, s);
        c1 = __fdiv_rn(c1, s);
        c2 = __fdiv_rn(c2, s);
        float p0 = __fmul_rn(fminf(fmaxf(c0, 0.0f), 1.0f), 7.0f);
        float p1 = __fmul_rn(fminf(fmaxf(c1, 0.0f), 1.0f), 7.0f);
        float p2 = __fmul_rn(fminf(fmaxf(c2, 0.0f), 1.0f), 7.0f);
        int i0 = (int)floorf(p0); i0 = i0 < 0 ? 0 : (i0 > 6 ? 6 : i0);
        int i1 = (int)floorf(p1); i1 = i1 < 0 ? 0 : (i1 > 6 ? 6 : i1);
        int i2 = (int)floorf(p2); i2 = i2 < 0 ? 0 : (i2 > 6 ? 6 : i2);
        float f0 = __fsub_rn(p0, (float)i0);
        float f1 = __fsub_rn(p1, (float)i1);
        float f2 = __fsub_rn(p2, (float)i2);
        const float* tb = tex + (size_t)f * (512 * 3);
        float a0 = 0.0f, a1 = 0.0f, a2 = 0.0f;
        #pragma unroll
        for (int d0 = 0; d0 < 2; ++d0) {
            float wx = d0 ? f0 : __fsub_rn(1.0f, f0);
            #pragma unroll
            for (int d1 = 0; d1 < 2; ++d1) {
                float wy = d1 ? f1 : __fsub_rn(1.0f, f1);
                #pragma unroll
                for (int d2 = 0; d2 < 2; ++d2) {
                    float wz = d2 ? f2 : __fsub_rn(1.0f, f2);
                    float w = __fmul_rn(__fmul_rn(wx, wy), wz);
                    int idx = (((i0 + d0) << 6) + ((i1 + d1) << 3) + (i2 + d2)) * 3;
                    a0 = __fadd_rn(a0, __fmul_rn(w, fmaxf(tb[idx + 0], 0.0f)));
                    a1 = __fadd_rn(a1, __fmul_rn(w, fmaxf(tb[idx + 1], 0.0f)));
                    a2 = __fadd_rn(a2, __fmul_rn(w, fmaxf(tb[idx + 2], 0.0f)));
                }
            }
        }
        o0 = a0; o1 = a1; o2 = a2; oa = 1.0f;
    } else {
        o0 = __fdiv_rn(bgc[0], 255.0f);
        o1 = __fdiv_rn(bgc[1], 255.0f);
        o2 = __fdiv_rn(bgc[2], 255.0f);
        oa = 0.0f;
    }
    out[3*p+0] = o0;
    out[3*p+1] = o1;
    out[3*p+2] = o2;
    out[(size_t)P*3 + p] = oa;
}

// ---------------------------------------------------------------------------
extern "C" void kernel_launch(void* const* d_in, const int* in_sizes, int n_in,
                              void* d_out, int out_size, void* d_ws, size_t ws_size,
                              hipStream_t stream)
{
    const float* verts = (const float*)d_in[0];
    const float* Km    = (const float*)d_in[1];
    const float* Rm    = (const float*)d_in[2];
    const float* tv    = (const float*)d_in[3];
    const float* bgc   = (const float*)d_in[4];
    const float* tex   = (const float*)d_in[5];
    const int*   faces = (const int*)d_in[6];
    int nV = in_sizes[0] / 3;
    int nF = in_sizes[6] / 3;
    int P = out_size / 4;                 // rgb(3P) + alpha(P)
    int W = (int)(sqrt((double)P) + 0.5);
    int H = W;
    int tilesX = (W + 7) / 8, tilesY = (H + 7) / 8;
    int nTiles = tilesX * tilesY;

    char* ws = (char*)d_ws;
    size_t o = 0;
    auto al = [](size_t x) { return (x + 255) & ~(size_t)255; };
    float*  sx  = (float*)(ws + o);  o = al(o + (size_t)nV * 4);
    float*  sy  = (float*)(ws + o);  o = al(o + (size_t)nV * 4);
    float*  sz  = (float*)(ws + o);  o = al(o + (size_t)nV * 4);
    float4* rec = (float4*)(ws + o); o = al(o + (size_t)nF * 48);
    float4* box = (float4*)(ws + o); o = al(o + (size_t)nF * 16);
    unsigned long long* zwin = (unsigned long long*)(ws + o);
    o = al(o + (size_t)P * 8);
    unsigned* cntseg = (unsigned*)(ws + o);
    o = al(o + (size_t)nTiles * NSEGC * 4);
    unsigned* ovf = (unsigned*)(ws + o);
    o = al(o + (size_t)nTiles * 4);
    unsigned short* list = (unsigned short*)(ws + o);
    size_t avail = (ws_size > o) ? ws_size - o : 0;
    int CAP = 0;
    if (nTiles > 0) {
        size_t c = avail / ((size_t)nTiles * 2);
        CAP = (int)(c > 8192 ? 8192 : c);
        CAP &= ~(NSEGC - 1);              // SUBCAP integral
    }
    int SUBCAP = CAP / NSEGC;
    (void)n_in;

    bool binned = (nTiles <= MAXTILES) && (nF < 65536) && (SUBCAP >= 64);

    k_prep_verts<<<dim3((nV + 63) / 64), dim3(64), 0, stream>>>(
        verts, Km, Rm, tv, sx, sy, sz, nV);
    k_prep_faces<<<dim3((nF + 63) / 64), dim3(64), 0, stream>>>(
        faces, sx, sy, sz, rec, box, zwin, ovf, nF, P, nTiles);

    if (binned) {
        dim3 g((nTiles + 3) / 4, NSEGC, 1);
        k_cull<<<g, dim3(256), 0, stream>>>(
            box, rec, cntseg, ovf, list, nF, tilesX, nTiles, CAP, SUBCAP);
        dim3 gr((nTiles + 3) / 4, NSEGR, 1);
        k_raster_bin<<<gr, dim3(256), 0, stream>>>(
            rec, cntseg, list, zwin, nF, W, H, tilesX, nTiles, CAP, SUBCAP);
        // overflow cleanup: exact full scan for flagged tiles (rare; normally
        // every block exits at the gate).
        dim3 gc((nTiles + 3) / 4, (nF + SEGSZ - 1) / SEGSZ, 1);
        k_raster_scan<<<gc, dim3(256), 0, stream>>>(
            rec, box, zwin, nF, W, H, tilesX, nTiles, ovf);
    } else {
        dim3 g((nTiles + 3) / 4, (nF + SEGSZ - 1) / SEGSZ, 1);
        k_raster_scan<<<g, dim3(256), 0, stream>>>(
            rec, box, zwin, nF, W, H, tilesX, nTiles, (const unsigned*)nullptr);
    }
    k_shade<<<dim3((P + 127) / 128), dim3(128), 0, stream>>>(
        rec, zwin, tex, bgc, (float*)d_out, W, H);
}

// Round 12
// 86.588 us; speedup vs baseline: 2.3883x; 2.3883x over previous
//
#include <hip/hip_runtime.h>
#include <math.h>

#define EPSF 1e-8f
#define BIGF 1e30f
#define NSEG 64        // face-window segments per tile

__device__ __forceinline__ float fastrcp(float x) {
    float y;
    asm("v_rcp_f32 %0, %1" : "=v"(y) : "v"(x));   // ~1 ulp; perf-filter only
    return y;
}

// ---------------------------------------------------------------------------
// Bit-exact projection of one vertex (numpy f32 op sequence, _rn ops only).
// Pure function of inputs -> identical bits wherever it is recomputed.
// ---------------------------------------------------------------------------
__device__ __forceinline__ void project_vert(
    const float* __restrict__ Km, const float* __restrict__ Rm,
    const float* __restrict__ tv,
    float vx, float vy, float vz, float& X, float& Y, float& Z)
{
    float a;
    a = __fadd_rn(__fmul_rn(vx, Rm[0]), __fmul_rn(vy, Rm[1]));
    a = __fadd_rn(a, __fmul_rn(vz, Rm[2]));
    float c0 = __fadd_rn(a, tv[0]);
    a = __fadd_rn(__fmul_rn(vx, Rm[3]), __fmul_rn(vy, Rm[4]));
    a = __fadd_rn(a, __fmul_rn(vz, Rm[5]));
    float c1 = __fadd_rn(a, tv[1]);
    a = __fadd_rn(__fmul_rn(vx, Rm[6]), __fmul_rn(vy, Rm[7]));
    a = __fadd_rn(a, __fmul_rn(vz, Rm[8]));
    float c2 = __fadd_rn(a, tv[2]);

    float u0 = __fadd_rn(__fadd_rn(__fmul_rn(c0, Km[0]), __fmul_rn(c1, Km[1])),
                         __fmul_rn(c2, Km[2]));
    float u1 = __fadd_rn(__fadd_rn(__fmul_rn(c0, Km[3]), __fmul_rn(c1, Km[4])),
                         __fmul_rn(c2, Km[5]));
    X = __fdiv_rn(u0, c2);
    Y = __fdiv_rn(u1, c2);
    Z = c2;
}

// ---------------------------------------------------------------------------
// Kernel 1: per-face setup straight from vertices (re-projects the 3 verts
// with the byte-identical sequence) + zwin init (grid-stride).
// rec[3f+0] = {y12, x21, y20, x02}
// rec[3f+1] = {x2,  y2,  denom, z0}
// rec[3f+2] = {z1,  z2,  face_id_bits, zmin}
// box[f]    = {xmin, xmax, ymin, ymax} (empty marker if invalid)
// ---------------------------------------------------------------------------
__global__ __launch_bounds__(64) void k_prep(
    const float* __restrict__ verts,
    const float* __restrict__ Km, const float* __restrict__ Rm,
    const float* __restrict__ tv, const int* __restrict__ faces,
    float4* __restrict__ rec, float4* __restrict__ box,
    unsigned long long* __restrict__ zwin, int nF, int P)
{
    int f = blockIdx.x * blockDim.x + threadIdx.x;
    int stride = gridDim.x * blockDim.x;
    unsigned long long initpk =
        ((unsigned long long)__float_as_uint(BIGF) << 32) | 0x7fffffffu;
    for (int i = f; i < P; i += stride) zwin[i] = initpk;
    if (f >= nF) return;

    int ia = faces[3*f+0], ib = faces[3*f+1], ic = faces[3*f+2];
    float x0, y0, z0, x1, y1, z1, x2, y2, z2;
    project_vert(Km, Rm, tv, verts[3*ia], verts[3*ia+1], verts[3*ia+2], x0, y0, z0);
    project_vert(Km, Rm, tv, verts[3*ib], verts[3*ib+1], verts[3*ib+2], x1, y1, z1);
    project_vert(Km, Rm, tv, verts[3*ic], verts[3*ic+1], verts[3*ic+2], x2, y2, z2);

    float y12 = __fsub_rn(y1, y2);
    float x21 = __fsub_rn(x2, x1);
    float y20 = __fsub_rn(y2, y0);
    float x02 = __fsub_rn(x0, x2);
    float y02 = __fsub_rn(y0, y2);
    float dn  = __fadd_rn(__fmul_rn(y12, x02), __fmul_rn(x21, y02));
    float zmin = fminf(fminf(z0, z1), z2);
    bool valid = (fabsf(dn) > EPSF) && (zmin > EPSF);
    float bxmin, bxmax, bymin, bymax;
    if (valid) {
        bxmin = fminf(fminf(x0, x1), x2) - 0.5f;
        bxmax = fmaxf(fmaxf(x0, x1), x2) + 0.5f;
        bymin = fminf(fminf(y0, y1), y2) - 0.5f;
        bymax = fmaxf(fmaxf(y0, y1), y2) + 0.5f;
    } else {
        bxmin = BIGF; bxmax = -BIGF; bymin = BIGF; bymax = -BIGF;
    }
    rec[3*f+0] = make_float4(y12, x21, y20, x02);
    rec[3*f+1] = make_float4(x2, y2, dn, z0);
    rec[3*f+2] = make_float4(z1, z2, __int_as_float(f), zmin);
    box[f]     = make_float4(bxmin, bxmax, bymin, bymax);
}

// ---------------------------------------------------------------------------
// Kernel 2: FUSED cull + z-test. Grid (tiles/4, NSEG); 256 thr = 4 indep
// waves; wave = (tile, 1/NSEG face window). Per 64-face chunk:
//   bbox test (16B/face, software-pipelined) -> conditional rec loads for
//   passers -> conservative edge-vs-tile reject -> ballot-compact stage to
//   LDS -> serial z-test of the ~7 survivors (zmin group-skip, rcp prefilter,
//   exact path byte-identical to reference).
// No lists, no caps, no cleanup: the scan is exact by construction.
// Winner merge: atomicMin on (depth_bits<<32|id) = reference's lexicographic
// (depth, lowest-id) rule; commutative -> deterministic.
// ---------------------------------------------------------------------------
__global__ __launch_bounds__(256) void k_raster(
    const float4* __restrict__ rec, const float4* __restrict__ box,
    unsigned long long* __restrict__ zwin,
    int nF, int W, int H, int tilesX, int nTiles)
{
    __shared__ float  sM[4][64];        // zmin (1 KB), also read as float4
    __shared__ float4 sZ[4][64];        // r2   (4 KB)
    __shared__ float4 sE[4][64][2];     // r0,r1 (8 KB)
    int wid  = threadIdx.x >> 6;
    int lane = threadIdx.x & 63;
    int tile = blockIdx.x * 4 + wid;
    if (tile >= nTiles) return;

    int segw = (nF + NSEG - 1) / NSEG;
    int fbeg = blockIdx.y * segw;
    int fend = min(nF, fbeg + segw);
    if (fbeg >= fend) return;

    int tileX = tile % tilesX, tileY = tile / tilesX;
    int tx = lane & 7, ty = lane >> 3;
    int pxi = tileX * 8 + tx;
    int pyi = tileY * 8 + ty;
    bool inimg = (pxi < W) && (pyi < H);
    float px = (float)pxi + 0.5f;
    float py = (float)pyi + 0.5f;
    float rx0 = (float)(tileX * 8) + 0.5f;
    float rx1 = rx0 + 7.0f;
    float ry0 = (float)(tileY * 8) + 0.5f;
    float ry1 = ry0 + 7.0f;
    float cx  = (float)(tileX * 8) + 4.0f;   // pixel centers span cx +/- 3.5
    float cy  = (float)(tileY * 8) + 4.0f;

    int pidx = inimg ? (pyi * W + pxi) : 0;
    unsigned long long seed = zwin[pidx];   // stale reads sound (monotone min)
    float bd = __uint_as_float((unsigned)(seed >> 32));
    int   bf = (int)(unsigned)(seed & 0xffffffffu);

    const float4* sM4g = (const float4*)sM[wid];

    // software pipeline: box load for chunk k+1 issues before chunk k's j-loop
    float4 nb = box[min(fbeg + lane, nF - 1)];

    for (int base = fbeg; base < fend; base += 64) {
        float4 cb = nb;
        if (base + 64 < fend) nb = box[min(base + 64 + lane, nF - 1)];
        int f = base + lane;
        bool pass = (f < fend) &&
                    (cb.x <= rx1) && (cb.y >= rx0) && (cb.z <= ry1) && (cb.w >= ry0);
        float4 r0, r1, r2;
        if (pass) {
            r0 = rec[3*f+0];
            r1 = rec[3*f+1];
            // conservative edge-vs-tile reject (3.6 > 3.5 px; perf-only)
            float s  = (r1.z > 0.0f) ? 1.0f : -1.0f;
            float dx = cx - r1.x, dy = cy - r1.y;
            float n0c = r0.x * dx + r0.y * dy;
            float n1c = r0.z * dx + r0.w * dy;
            float t0 = s * n0c + 3.6f * (fabsf(r0.x) + fabsf(r0.y));
            float t1 = s * n1c + 3.6f * (fabsf(r0.z) + fabsf(r0.w));
            float t2 = s * (r1.z - n0c - n1c)
                     + 3.6f * (fabsf(r0.x + r0.z) + fabsf(r0.y + r0.w));
            pass = (t0 >= 0.0f) && (t1 >= 0.0f) && (t2 >= 0.0f);
        }
        if (pass) r2 = rec[3*f+2];
        unsigned long long m = __ballot(pass);
        if (pass) {
            int slot = __popcll(m & ((1ull << lane) - 1ull));
            sM[wid][slot]    = r2.w;
            sZ[wid][slot]    = r2;
            sE[wid][slot][0] = r0;
            sE[wid][slot][1] = r1;
        }
        int scnt = (int)__popcll(m);

        for (int g = 0; g < scnt; g += 4) {
            // group skip: min of 4 zmins (stale tail slots only weaken the
            // skip -> conservative); one b128 broadcast + one ballot.
            float4 z4 = sM4g[g >> 2];
            float zg = fminf(fminf(z4.x, z4.y), fminf(z4.z, z4.w));
            if (!__any(zg <= __fmul_rn(bd, 1.001f))) continue;
            int jend = min(scnt, g + 4);
            for (int j = g; j < jend; ++j) {
                if (!__any(sM[wid][j] <= __fmul_rn(bd, 1.001f))) continue;
                float4 r2b = sZ[wid][j];
                float4 r0b = sE[wid][j][0];
                float4 r1b = sE[wid][j][1];

                float dx = __fsub_rn(px, r1b.x);
                float dy = __fsub_rn(py, r1b.y);
                float n0 = __fadd_rn(__fmul_rn(r0b.x, dx), __fmul_rn(r0b.y, dy));
                float n1 = __fadd_rn(__fmul_rn(r0b.z, dx), __fmul_rn(r0b.w, dy));
                float dn = r1b.z;
                bool dpos = dn > 0.0f;
                bool in0 = (n0 == 0.0f) || ((n0 > 0.0f) == dpos);  // n0/dn >= 0
                bool in1 = (n1 == 0.0f) || ((n1 > 0.0f) == dpos);
                bool cand = in0 && in1;
                if (cand) {
                    float rdn = fastrcp(dn);
                    float w0a = n0 * rdn, w1a = n1 * rdn;
                    float w2a = 1.0f - w0a - w1a;
                    float ss  = 1.0f + fabsf(w0a) + fabsf(w1a);
                    cand = (w2a >= -1e-4f * ss);       // err(w2a) <= 3e-7*ss
                    if (cand) {
                        float iza = w0a * fastrcp(r1b.w) + w1a * fastrcp(r2b.x)
                                  + w2a * fastrcp(r2b.y);
                        float da  = fastrcp(iza);
                        cand = (da <= __fmul_rn(bd, 1.001f));  // err ~1.5e-4
                    }
                }
                if (cand) {   // exact path: byte-identical reference op order
                    float w0 = __fdiv_rn(n0, dn);
                    float w1 = __fdiv_rn(n1, dn);
                    float w2 = __fsub_rn(__fsub_rn(1.0f, w0), w1);
                    if (w2 >= 0.0f) {
                        float a  = __fdiv_rn(w0, r1b.w);
                        float b2 = __fdiv_rn(w1, r2b.x);
                        float c  = __fdiv_rn(w2, r2b.y);
                        float iz = __fadd_rn(__fadd_rn(a, b2), c);
                        if (iz > EPSF) {
                            float d = __fdiv_rn(1.0f, iz);
                            int  fc = __float_as_int(r2b.z);
                            if ((d < bd) || ((d == bd) && (fc < bf))) {
                                bd = d; bf = fc;
                            }
                        }
                    }
                }
            }
        }
    }

    unsigned long long pk =
        ((unsigned long long)__float_as_uint(bd) << 32) | (unsigned int)bf;
    if (inimg && pk < seed) atomicMin(&zwin[pidx], pk);
}

// ---------------------------------------------------------------------------
// Kernel 3: shade. One thread per pixel; recompute winner bary (bit-identical
// op sequence) and trilinear-sample its 8^3 texture.
// ---------------------------------------------------------------------------
__global__ __launch_bounds__(128) void k_shade(
    const float4* __restrict__ rec,
    const unsigned long long* __restrict__ zwin,
    const float* __restrict__ tex, const float* __restrict__ bgc,
    float* __restrict__ out, int W, int H)
{
    int p = blockIdx.x * blockDim.x + threadIdx.x;
    int P = W * H;
    if (p >= P) return;
    int pxi = p % W, pyi = p / W;
    float px = (float)pxi + 0.5f;
    float py = (float)pyi + 0.5f;

    unsigned long long pk = zwin[p];
    float o0, o1, o2, oa;
    if ((unsigned)(pk >> 32) != __float_as_uint(BIGF)) {
        int f = (int)(pk & 0xffffffffu);
        float4 r0 = rec[3*f+0];
        float4 r1 = rec[3*f+1];
        float4 r2 = rec[3*f+2];
        float dx = __fsub_rn(px, r1.x);
        float dy = __fsub_rn(py, r1.y);
        float n0 = __fadd_rn(__fmul_rn(r0.x, dx), __fmul_rn(r0.y, dy));
        float n1 = __fadd_rn(__fmul_rn(r0.z, dx), __fmul_rn(r0.w, dy));
        float w0 = __fdiv_rn(n0, r1.z);
        float w1 = __fdiv_rn(n1, r1.z);
        float w2 = __fsub_rn(__fsub_rn(1.0f, w0), w1);
        float c0 = __fdiv_rn(w0, fmaxf(r1.w, EPSF));
        float c1 = __fdiv_rn(w1, fmaxf(r2.x, EPSF));
        float c2 = __fdiv_rn(w2, fmaxf(r2.y, EPSF));
        float s  = __fadd_rn(__fadd_rn(c0, c1), c2);
        s = fmaxf(s, EPSF);
        c0 = __fdiv_rn(c0, s);
        c1 = __fdiv_rn(c1, s);
        c2 = __fdiv_rn(c2, s);
        float p0 = __fmul_rn(fminf(fmaxf(c0, 0.0f), 1.0f), 7.0f);
        float p1 = __fmul_rn(fminf(fmaxf(c1, 0.0f), 1.0f), 7.0f);
        float p2 = __fmul_rn(fminf(fmaxf(c2, 0.0f), 1.0f), 7.0f);
        int i0 = (int)floorf(p0); i0 = i0 < 0 ? 0 : (i0 > 6 ? 6 : i0);
        int i1 = (int)floorf(p1); i1 = i1 < 0 ? 0 : (i1 > 6 ? 6 : i1);
        int i2 = (int)floorf(p2); i2 = i2 < 0 ? 0 : (i2 > 6 ? 6 : i2);
        float f0 = __fsub_rn(p0, (float)i0);
        float f1 = __fsub_rn(p1, (float)i1);
        float f2 = __fsub_rn(p2, (float)i2);
        const float* tb = tex + (size_t)f * (512 * 3);
        float a0 = 0.0f, a1 = 0.0f, a2 = 0.0f;
        #pragma unroll
        for (int d0 = 0; d0 < 2; ++d0) {
            float wx = d0 ? f0 : __fsub_rn(1.0f, f0);
            #pragma unroll
            for (int d1 = 0; d1 < 2; ++d1) {
                float wy = d1 ? f1 : __fsub_rn(1.0f, f1);
                #pragma unroll
                for (int d2 = 0; d2 < 2; ++d2) {
                    float wz = d2 ? f2 : __fsub_rn(1.0f, f2);
                    float w = __fmul_rn(__fmul_rn(wx, wy), wz);
                    int idx = (((i0 + d0) << 6) + ((i1 + d1) << 3) + (i2 + d2)) * 3;
                    a0 = __fadd_rn(a0, __fmul_rn(w, fmaxf(tb[idx + 0], 0.0f)));
                    a1 = __fadd_rn(a1, __fmul_rn(w, fmaxf(tb[idx + 1], 0.0f)));
                    a2 = __fadd_rn(a2, __fmul_rn(w, fmaxf(tb[idx + 2], 0.0f)));
                }
            }
        }
        o0 = a0; o1 = a1; o2 = a2; oa = 1.0f;
    } else {
        o0 = __fdiv_rn(bgc[0], 255.0f);
        o1 = __fdiv_rn(bgc[1], 255.0f);
        o2 = __fdiv_rn(bgc[2], 255.0f);
        oa = 0.0f;
    }
    out[3*p+0] = o0;
    out[3*p+1] = o1;
    out[3*p+2] = o2;
    out[(size_t)P*3 + p] = oa;
}

// ---------------------------------------------------------------------------
extern "C" void kernel_launch(void* const* d_in, const int* in_sizes, int n_in,
                              void* d_out, int out_size, void* d_ws, size_t ws_size,
                              hipStream_t stream)
{
    const float* verts = (const float*)d_in[0];
    const float* Km    = (const float*)d_in[1];
    const float* Rm    = (const float*)d_in[2];
    const float* tv    = (const float*)d_in[3];
    const float* bgc   = (const float*)d_in[4];
    const float* tex   = (const float*)d_in[5];
    const int*   faces = (const int*)d_in[6];
    int nF = in_sizes[6] / 3;
    int P = out_size / 4;                 // rgb(3P) + alpha(P)
    int W = (int)(sqrt((double)P) + 0.5);
    int H = W;
    int tilesX = (W + 7) / 8, tilesY = (H + 7) / 8;
    int nTiles = tilesX * tilesY;

    char* ws = (char*)d_ws;
    size_t o = 0;
    auto al = [](size_t x) { return (x + 255) & ~(size_t)255; };
    float4* rec = (float4*)(ws + o); o = al(o + (size_t)nF * 48);
    float4* box = (float4*)(ws + o); o = al(o + (size_t)nF * 16);
    unsigned long long* zwin = (unsigned long long*)(ws + o);
    o = al(o + (size_t)P * 8);
    (void)ws_size; (void)n_in;           // ~1.5 MB total scratch

    k_prep<<<dim3((nF + 63) / 64), dim3(64), 0, stream>>>(
        verts, Km, Rm, tv, faces, rec, box, zwin, nF, P);
    dim3 g((nTiles + 3) / 4, NSEG, 1);
    k_raster<<<g, dim3(256), 0, stream>>>(
        rec, box, zwin, nF, W, H, tilesX, nTiles);
    k_shade<<<dim3((P + 127) / 128), dim3(128), 0, stream>>>(
        rec, zwin, tex, bgc, (float*)d_out, W, H);
}